// Round 8
// baseline (39765.814 us; speedup 1.0000x reference)
//
#include <hip/hip_runtime.h>

// ---------------------------------------------------------------------------
// TransitionDown: FPS (M=N/4) -> KNN(K=16) -> Linear(64->128)+ReLU -> max-pool
// Round 12: single-wave FPS, zero barriers. r11 (8 waves, 3 barriers/step,
// step 1.43us) was ~65% stall: barriers + cross-wave LDS handshakes + the
// dependent posx[og] pick load. One 64-lane wave makes every phase
// wave-internal and in-order:
//   - phase 1: 8 bound tests/lane (bbox in 48 regs), 8 ballots -> masks.
//   - phase 2: batches of 8 active chunks x 8 lanes; k-th-set-bit per lane
//     via unrolled ffs/cndmask ladder (no runtime-indexed local array);
//     points packed float4{x,y,z,bitcast(orig)} -> 1 dwordx4/point; mind rmw
//     2x ds_b128 with r11's XOR bit[2:5] swizzle; in-lane u64 key fold; only
//     3 DPP levels per 8-lane group.
//   - phase 3: in-lane fold over 512 packed chunk keys + 6-level DPP u64
//     tree CARRYING THE WINNER'S COORDS as payload (keys unique: orig is in
//     the key) -> next pick coords via readlane, no global load.
// Exactness preserved from passed rounds r9-r11: skip rule dlb*0.99999 >=
// cmax (fmin identity => skipped/extra updates exact), key (mbits<<32)|~orig
// (max == max-value-then-lowest-orig-index), identical distance/bound
// expressions, r11-validated DPP ladder (lane 63 holds result).
// ---------------------------------------------------------------------------

#define NC      512
#define KNN_K   16
#define MLP_ROWS 32

#define DPPF(X, CTRL) __uint_as_float(__builtin_amdgcn_update_dpp(            \
    (int)__float_as_uint(X), (int)__float_as_uint(X), (CTRL), 0xf, 0xf, false))
#define DPPU(X, CTRL) ((unsigned)__builtin_amdgcn_update_dpp(                 \
    (int)(X), (int)(X), (CTRL), 0xf, 0xf, false))

// 64-bit max-combine with coordinate payload. old=src (bound_ctrl=false):
// lanes with no valid partner combine with self (no-op). Keys are unique
// (orig embedded) so payload selection is deterministic.
#define DPPMAX64P(KK, PX_, PY_, PZ_, CTRL)                                    \
    {                                                                         \
        const unsigned _lo = (unsigned)(KK), _hi = (unsigned)((KK) >> 32);    \
        const unsigned _nlo = DPPU(_lo, CTRL), _nhi = DPPU(_hi, CTRL);        \
        const float _nx = DPPF(PX_, CTRL);                                    \
        const float _ny = DPPF(PY_, CTRL);                                    \
        const float _nz = DPPF(PZ_, CTRL);                                    \
        const unsigned long long _nk =                                        \
            ((unsigned long long)_nhi << 32) | _nlo;                          \
        if (_nk > (KK)) { KK = _nk; PX_ = _nx; PY_ = _ny; PZ_ = _nz; }        \
    }

// --- SoA transpose of pos for coalesced per-coordinate access ---------------
__global__ void prep_kernel(const float* __restrict__ pos, float* __restrict__ posx,
                            float* __restrict__ posy, float* __restrict__ posz, int N)
{
    const int i = blockIdx.x * blockDim.x + threadIdx.x;
    if (i < N) {
        posx[i] = pos[3 * i + 0];
        posy[i] = pos[3 * i + 1];
        posz[i] = pos[3 * i + 2];
    }
}

// --- Morton-bucket counting sort -> packed pts {x,y,z,bitcast(orig)} --------
__device__ __forceinline__ unsigned spread4(unsigned x)
{
    return (x & 1u) | ((x & 2u) << 2) | ((x & 4u) << 4) | ((x & 8u) << 6);
}
__device__ __forceinline__ unsigned mcode(float x, float y, float z)
{
    int qx = (int)((x + 6.0f) * (16.0f / 12.0f));
    int qy = (int)((y + 6.0f) * (16.0f / 12.0f));
    int qz = (int)((z + 6.0f) * (16.0f / 12.0f));
    qx = qx < 0 ? 0 : (qx > 15 ? 15 : qx);
    qy = qy < 0 ? 0 : (qy > 15 ? 15 : qy);
    qz = qz < 0 ? 0 : (qz > 15 ? 15 : qz);
    return spread4((unsigned)qx) | (spread4((unsigned)qy) << 1)
         | (spread4((unsigned)qz) << 2);
}

__global__ __launch_bounds__(1024) void sort_kernel(
    const float* __restrict__ posx, const float* __restrict__ posy,
    const float* __restrict__ posz, float4* __restrict__ pts, int N)
{
    __shared__ unsigned cnt[4096];
    __shared__ unsigned base[4096];
    const int t = threadIdx.x;

    for (int i = t; i < 4096; i += 1024) cnt[i] = 0;
    __syncthreads();
    for (int i = t; i < N; i += 1024)
        atomicAdd(&cnt[mcode(posx[i], posy[i], posz[i])], 1u);
    __syncthreads();
    if (t == 0) {
        unsigned run = 0;
        for (int c = 0; c < 4096; ++c) { base[c] = run; run += cnt[c]; }
    }
    __syncthreads();
    for (int i = t; i < 4096; i += 1024) cnt[i] = 0;
    __syncthreads();
    for (int i = t; i < N; i += 1024) {
        const float px = posx[i], py = posy[i], pz = posz[i];
        const unsigned m = mcode(px, py, pz);
        const unsigned d = base[m] + atomicAdd(&cnt[m], 1u);
        pts[d] = make_float4(px, py, pz, __uint_as_float((unsigned)i));
    }
}

// --- per-chunk bbox (exact fmin/fmax of member coords) ----------------------
__global__ __launch_bounds__(64) void bbox_kernel(
    const float4* __restrict__ pts, float* __restrict__ bboxG)
{
    const int c = blockIdx.x, l = threadIdx.x;
    const float4 p = pts[c * 64 + l];
    float xmn = p.x, xmx = p.x;
    float ymn = p.y, ymx = p.y;
    float zmn = p.z, zmx = p.z;
#pragma unroll
    for (int off = 32; off > 0; off >>= 1) {
        xmn = fminf(xmn, __shfl_xor(xmn, off));
        xmx = fmaxf(xmx, __shfl_xor(xmx, off));
        ymn = fminf(ymn, __shfl_xor(ymn, off));
        ymx = fmaxf(ymx, __shfl_xor(ymx, off));
        zmn = fminf(zmn, __shfl_xor(zmn, off));
        zmx = fmaxf(zmx, __shfl_xor(zmx, off));
    }
    if (l == 0) {
        float* o = &bboxG[c * 6];
        o[0] = xmn; o[1] = xmx; o[2] = ymn; o[3] = ymx; o[4] = zmn; o[5] = zmx;
    }
}

// --- h = relu(x @ W + b), x[N,64], W[64,128], h[N,128] ----------------------
__global__ __launch_bounds__(256) void mlp_kernel(
    const float* __restrict__ x, const float* __restrict__ W,
    const float* __restrict__ b, float* __restrict__ h, int N)
{
    __shared__ float ws[64 * 128];
    __shared__ float xs[MLP_ROWS * 65];   // +1 pad: breaks 8-way bank conflict
    const int t = threadIdx.x;
    const int r0 = blockIdx.x * MLP_ROWS;

    for (int i = t; i < 64 * 128; i += 256) ws[i] = W[i];
    for (int i = t; i < MLP_ROWS * 64; i += 256) {
        const int r = i >> 6, k = i & 63;
        xs[r * 65 + k] = x[r0 * 64 + i];
    }
    __syncthreads();

    const int tx = t & 31, ty = t >> 5;
    const int c0 = tx * 4, rr = ty * 4;    // 4 rows x 4 cols per thread
    float acc[4][4];
#pragma unroll
    for (int i = 0; i < 4; ++i)
#pragma unroll
        for (int j = 0; j < 4; ++j) acc[i][j] = 0.0f;

    for (int k = 0; k < 64; ++k) {
        const float4 w4 = *(const float4*)(&ws[k * 128 + c0]);
#pragma unroll
        for (int i = 0; i < 4; ++i) {
            const float xv = xs[(rr + i) * 65 + k];
            acc[i][0] += xv * w4.x;
            acc[i][1] += xv * w4.y;
            acc[i][2] += xv * w4.z;
            acc[i][3] += xv * w4.w;
        }
    }
    const float4 b4 = *(const float4*)(&b[c0]);
#pragma unroll
    for (int i = 0; i < 4; ++i) {
        float4 o;
        o.x = fmaxf(acc[i][0] + b4.x, 0.0f);
        o.y = fmaxf(acc[i][1] + b4.y, 0.0f);
        o.z = fmaxf(acc[i][2] + b4.z, 0.0f);
        o.w = fmaxf(acc[i][3] + b4.w, 0.0f);
        *(float4*)(&h[(size_t)(r0 + rr + i) * 128 + c0]) = o;
    }
}

// --- Farthest point sampling: exact, chunk-pruned, single-wave --------------
__global__ __launch_bounds__(64)
__attribute__((amdgpu_waves_per_eu(1)))
void fps_kernel(
    const float4* __restrict__ pts, const float* __restrict__ bboxG,
    const float* __restrict__ pos, int* __restrict__ out_idx, int M)
{
    __shared__ __align__(16) float mind[32768];   // 128 KB, sorted order
    __shared__ float cmax[NC];                    // max(mind) per chunk
    __shared__ __align__(16) uint4 ckey4[NC];     // {keyhi, keylo, xbits, ybits}
    __shared__ float ckz[NC];                     // winner z per chunk

    const int t = threadIdx.x;                    // 0..63
    const int sg = t & 7;                         // lane within 8-lane group
    const int grp = t >> 3;                       // group id (chunk slot)

    for (int i = t; i < 32768; i += 64) mind[i] = __builtin_inff();
    for (int c = t; c < NC; c += 64) cmax[c] = __builtin_inff();

    // bbox registers: lane t owns chunks {t, t+64, ..., t+448}
    float bx0[8], bx1[8], by0[8], by1[8], bz0[8], bz1[8];
#pragma unroll
    for (int j = 0; j < 8; ++j) {
        const float* bs = &bboxG[(j * 64 + t) * 6];
        bx0[j] = bs[0]; bx1[j] = bs[1];
        by0[j] = bs[2]; by1[j] = bs[3];
        bz0[j] = bs[4]; bz1[j] = bs[5];
    }
    if (t == 0) out_idx[0] = 0;
    float lx = pos[0], ly = pos[1], lz = pos[2];  // pick 0 = original index 0
    __syncthreads();

    for (int s = 1; s < M; ++s) {
        // ---- phase 1: bound tests (8 chunks/lane) -> 8 uniform masks -------
        unsigned long long msk[8];
#pragma unroll
        for (int j = 0; j < 8; ++j) {
            const int c = j * 64 + t;
            const float gx = fmaxf(fmaxf(bx0[j] - lx, lx - bx1[j]), 0.0f);
            const float gy = fmaxf(fmaxf(by0[j] - ly, ly - by1[j]), 0.0f);
            const float gz = fmaxf(fmaxf(bz0[j] - lz, lz - bz1[j]), 0.0f);
            const float dlb = (gx * gx + gy * gy + gz * gz) * 0.99999f;
            msk[j] = __ballot(dlb < cmax[c]);
        }

        // ---- phase 2: batches of 8 active chunks, 8 lanes each -------------
#pragma unroll 1
        for (int j = 0; j < 8; ++j) {
            unsigned long long m = msk[j];
            while (m) {
                const int k = min(8, (int)__popcll(m));
                // lane's chunk = grp-th set bit (unrolled ladder, no array)
                unsigned long long mm = m;
                int myb = 0;
#pragma unroll
                for (int q = 0; q < 8; ++q) {
                    const int bpos = __ffsll((long long)mm) - 1;
                    if (q == grp) myb = bpos < 0 ? 0 : bpos;
                    mm &= mm - 1;
                }
                m = mm;                              // 8 lowest bits consumed
                const int cc = (j << 6) + myb;
                const bool active = (grp < k);

                // one dwordx4 per point: {x, y, z, bitcast(orig)}
                float4 p[8];
                const int pbase = (cc << 6) + (sg << 3);
#pragma unroll
                for (int q = 0; q < 8; ++q) p[q] = pts[pbase + q];

                const int swz = (cc & 15) << 2;
                const int o0 = (cc << 6) + ((sg << 3) ^ swz);
                const int o1 = (cc << 6) + (((sg << 3) + 4) ^ swz);
                float4 m0 = *(const float4*)&mind[o0];
                float4 m1 = *(const float4*)&mind[o1];

                unsigned long long bkey = 0ULL;
                float bpx = 0.0f, bpy = 0.0f, bpz = 0.0f;
#define PT(q, MC)                                                             \
                {                                                             \
                    const float dx = p[q].x - lx;                             \
                    const float dy = p[q].y - ly;                             \
                    const float dz = p[q].z - lz;                             \
                    const float d = dx * dx + dy * dy + dz * dz;              \
                    MC = fminf(MC, d);                                        \
                    const unsigned long long kq =                             \
                        ((unsigned long long)__float_as_uint(MC) << 32)       \
                        | (unsigned)~__float_as_uint(p[q].w);                 \
                    if (kq > bkey) {                                          \
                        bkey = kq; bpx = p[q].x; bpy = p[q].y; bpz = p[q].z;  \
                    }                                                         \
                }
                PT(0, m0.x) PT(1, m0.y) PT(2, m0.z) PT(3, m0.w)
                PT(4, m1.x) PT(5, m1.y) PT(6, m1.z) PT(7, m1.w)
#undef PT
                if (active) {
                    *(float4*)&mind[o0] = m0;
                    *(float4*)&mind[o1] = m1;
                }
                // 8-lane group reduce: xor1, xor2, half-mirror
                DPPMAX64P(bkey, bpx, bpy, bpz, 0xB1)
                DPPMAX64P(bkey, bpx, bpy, bpz, 0x4E)
                DPPMAX64P(bkey, bpx, bpy, bpz, 0x141)
                if (active && sg == 0) {
                    ckey4[cc] = make_uint4((unsigned)(bkey >> 32),
                                           (unsigned)bkey,
                                           __float_as_uint(bpx),
                                           __float_as_uint(bpy));
                    ckz[cc] = bpz;
                    cmax[cc] = __uint_as_float((unsigned)(bkey >> 32));
                }
            }
        }

        // ---- phase 3: global argmax over 512 chunk keys + payload ----------
        unsigned long long gk = 0ULL;
        float gpx = 0.0f, gpy = 0.0f, gpz = 0.0f;
#pragma unroll
        for (int j = 0; j < 8; ++j) {
            const int c = j * 64 + t;
            const uint4 k4 = ckey4[c];
            const float kz = ckz[c];
            const unsigned long long kk =
                ((unsigned long long)k4.x << 32) | k4.y;
            if (kk > gk) {
                gk = kk;
                gpx = __uint_as_float(k4.z);
                gpy = __uint_as_float(k4.w);
                gpz = kz;
            }
        }
        DPPMAX64P(gk, gpx, gpy, gpz, 0xB1)
        DPPMAX64P(gk, gpx, gpy, gpz, 0x4E)
        DPPMAX64P(gk, gpx, gpy, gpz, 0x141)
        DPPMAX64P(gk, gpx, gpy, gpz, 0x140)
        DPPMAX64P(gk, gpx, gpy, gpz, 0x142)
        DPPMAX64P(gk, gpx, gpy, gpz, 0x143)
        // lane 63 holds (max key, winner coords) — broadcast via readlane
        const unsigned glo =
            (unsigned)__builtin_amdgcn_readlane((int)(unsigned)gk, 63);
        if (t == 0) out_idx[s] = (int)~glo;
        lx = __uint_as_float(
            (unsigned)__builtin_amdgcn_readlane((int)__float_as_uint(gpx), 63));
        ly = __uint_as_float(
            (unsigned)__builtin_amdgcn_readlane((int)__float_as_uint(gpy), 63));
        lz = __uint_as_float(
            (unsigned)__builtin_amdgcn_readlane((int)__float_as_uint(gpz), 63));
    }
}

// --- KNN (exact top-16 by (d, idx)) + gather-max over h + sub outputs -------
__global__ __launch_bounds__(256) void knn_kernel(
    const float* __restrict__ posx, const float* __restrict__ posy,
    const float* __restrict__ posz, const int* __restrict__ idx,
    const float* __restrict__ h, const float* __restrict__ pos,
    const int* __restrict__ batch, float* __restrict__ out,
    float* __restrict__ out_subpos, int* __restrict__ out_subbatch,
    int N, int M, int Cout)
{
    const int q = (int)((blockIdx.x * (unsigned)blockDim.x + threadIdx.x) >> 6);
    const int lane = threadIdx.x & 63;
    if (q >= M) return;

    const int qi = idx[q];
    const float qx = posx[qi], qy = posy[qi], qz = posz[qi];

    // per-lane top-16 (replace-max), wave-shared rejection threshold T
    float d16[KNN_K]; int i16[KNN_K];
#pragma unroll
    for (int k = 0; k < KNN_K; ++k) { d16[k] = __builtin_inff(); i16[k] = 0x7fffffff; }
    float lmax = __builtin_inff();
    int lslot = 0;
    float T = __builtin_inff();

    const int iters = N >> 6;
    for (int c = 0; c < iters; ++c) {
        const int p = c * 64 + lane;
        const float dx = posx[p] - qx;
        const float dy = posy[p] - qy;
        const float dz = posz[p] - qz;
        const float d = dx * dx + dy * dy + dz * dz;
        if (d < T && d < lmax) {
            d16[lslot] = d; i16[lslot] = p;
            lmax = d16[0]; lslot = 0;
#pragma unroll
            for (int k = 1; k < KNN_K; ++k)
                if (d16[k] > lmax) { lmax = d16[k]; lslot = k; }
        }
        if ((c & 31) == 31) {
            float tt = lmax;
#pragma unroll
            for (int off = 32; off > 0; off >>= 1)
                tt = fminf(tt, __shfl_xor(tt, off));
            T = tt;   // global-16th-so-far <= min over lanes of lane-16th: exact reject
        }
    }

    // merge: 16 rounds of wave extract-min with (d, idx) lexicographic order
    int nbr[KNN_K];
#pragma unroll
    for (int r = 0; r < KNN_K; ++r) {
        float lv = d16[0]; int ls = 0;
#pragma unroll
        for (int k = 1; k < KNN_K; ++k)
            if (d16[k] < lv || (d16[k] == lv && i16[k] < i16[ls])) { lv = d16[k]; ls = k; }
        float mv = lv; int mi = i16[ls];
#pragma unroll
        for (int off = 32; off > 0; off >>= 1) {
            const float ov = __shfl_xor(mv, off);
            const int   oi = __shfl_xor(mi, off);
            if (ov < mv || (ov == mv && oi < mi)) { mv = ov; mi = oi; }
        }
        if (i16[ls] == mi) d16[ls] = __builtin_inff();   // unique owner removes it
        nbr[r] = mi;
    }

    // out[q] = max over 16 neighbors of h rows (coalesced per-row loads)
    for (int c = lane; c < Cout; c += 64) {
        float a = -__builtin_inff();
#pragma unroll
        for (int r = 0; r < KNN_K; ++r)
            a = fmaxf(a, h[(size_t)nbr[r] * Cout + c]);
        out[(size_t)q * Cout + c] = a;
    }
    if (lane < 3) out_subpos[q * 3 + lane] = pos[qi * 3 + lane];
    if (lane == 3) out_subbatch[q] = batch[qi];
}

// ---------------------------------------------------------------------------
extern "C" void kernel_launch(void* const* d_in, const int* in_sizes, int n_in,
                              void* d_out, int out_size, void* d_ws, size_t ws_size,
                              hipStream_t stream)
{
    const float* x     = (const float*)d_in[0];
    const float* pos   = (const float*)d_in[1];
    const int*   batch = (const int*)d_in[2];
    const float* W     = (const float*)d_in[3];
    const float* b     = (const float*)d_in[4];

    const int N    = in_sizes[2];       // 32768 (batch has one entry per point)
    const int Cout = in_sizes[4];       // 128
    const int M    = N / 4;             // RATIO = 0.25 -> 8192

    // workspace layout (floats): posx | posy | posz | idx(int) | h[N*Cout]
    float* posx = (float*)d_ws;
    float* posy = posx + N;
    float* posz = posy + N;
    int*   idx  = (int*)(posz + N);
    float* h    = (float*)(idx + M);

    // sort/bbox scratch ALIASES the h region (fps finishes before mlp writes
    // h; single stream serializes): pts (4N floats) | bboxG (3072 floats).
    float4* pts   = (float4*)h;
    float*  bboxG = (float*)(pts + N);

    float* out          = (float*)d_out;
    float* out_subpos   = out + (size_t)M * Cout;
    int*   out_subbatch = (int*)(out_subpos + (size_t)M * 3);

    prep_kernel<<<(N + 255) / 256, 256, 0, stream>>>(pos, posx, posy, posz, N);
    sort_kernel<<<1, 1024, 0, stream>>>(posx, posy, posz, pts, N);
    bbox_kernel<<<NC, 64, 0, stream>>>(pts, bboxG);
    fps_kernel<<<1, 64, 0, stream>>>(pts, bboxG, pos, idx, M);
    mlp_kernel<<<N / MLP_ROWS, 256, 0, stream>>>(x, W, b, h, N);
    knn_kernel<<<(M * 64) / 256, 256, 0, stream>>>(posx, posy, posz, idx, h, pos, batch,
                                                   out, out_subpos, out_subbatch, N, M, Cout);
}

// Round 9
// 14186.386 us; speedup vs baseline: 2.8031x; 2.8031x over previous
//
#include <hip/hip_runtime.h>

// ---------------------------------------------------------------------------
// TransitionDown: FPS (M=N/4) -> KNN(K=16) -> Linear(64->128)+ReLU -> max-pool
// Round 13: 8 waves (r11 structure, best at 1.43us/step) + r12's payload-carry
// ideas, minus r12's fatal single-wave latency exposure (r12: 1 wave, zero
// TLP, every 120cyc LDS / 300cyc L2 access serial -> 4.6us/step).
// 2 barriers/step (was 3) and no dependent pick-coord load:
//   segment 1 (redundant in all 8 waves): global argmax over 512 chunk keys
//     = 8 ckey u64 folds/lane + 6-level DPP ladder carrying chunk id payload
//     -> pick known wave-locally; coords via one broadcast LDS read
//     (cpx/cpy/cpz[cid]).  Then bound test (bbox in regs) + alist push.
//   barrier A; segment 2: r11/r12-validated 8-thr/chunk update (packed pts
//     float4, mind b128 rmw + XOR swizzle, in-lane u64 fold, 3-level DPP with
//     coord payload) -> ckey/cmax/cpx/cpy/cpz.  barrier B.
// Prologue applies pick-0 update to all 512 chunks => loop's argmax-first
// order reproduces the reference pick sequence exactly.
// Exactness pieces all from passed rounds: skip rule dlb*0.99999>=cmax (fmin
// identity), key (mbits<<32)|~orig (max == max-val-then-lowest-orig), r8/r11/
// r12-validated DPP ladders, r9/r11 alist+dbuf-acnt discipline.
// ---------------------------------------------------------------------------

#define FPS_T   512
#define NC      512
#define KNN_K   16
#define MLP_ROWS 32

#define DPPF(X, CTRL) __uint_as_float(__builtin_amdgcn_update_dpp(            \
    (int)__float_as_uint(X), (int)__float_as_uint(X), (CTRL), 0xf, 0xf, false))
#define DPPU(X, CTRL) ((unsigned)__builtin_amdgcn_update_dpp(                 \
    (int)(X), (int)(X), (CTRL), 0xf, 0xf, false))

// u64 max-combine with 3-float coord payload (r12-validated).
#define DPPMAX64P(KK, PX_, PY_, PZ_, CTRL)                                    \
    {                                                                         \
        const unsigned _lo = (unsigned)(KK), _hi = (unsigned)((KK) >> 32);    \
        const unsigned _nlo = DPPU(_lo, CTRL), _nhi = DPPU(_hi, CTRL);        \
        const float _nx = DPPF(PX_, CTRL);                                    \
        const float _ny = DPPF(PY_, CTRL);                                    \
        const float _nz = DPPF(PZ_, CTRL);                                    \
        const unsigned long long _nk =                                        \
            ((unsigned long long)_nhi << 32) | _nlo;                          \
        if (_nk > (KK)) { KK = _nk; PX_ = _nx; PY_ = _ny; PZ_ = _nz; }        \
    }

// u64 max-combine with u32 chunk-id payload.
#define DPPMAX64C(KK, CC_, CTRL)                                              \
    {                                                                         \
        const unsigned _lo = (unsigned)(KK), _hi = (unsigned)((KK) >> 32);    \
        const unsigned _nlo = DPPU(_lo, CTRL), _nhi = DPPU(_hi, CTRL);        \
        const unsigned _nc = DPPU(CC_, CTRL);                                 \
        const unsigned long long _nk =                                        \
            ((unsigned long long)_nhi << 32) | _nlo;                          \
        if (_nk > (KK)) { KK = _nk; CC_ = _nc; }                              \
    }

// --- SoA transpose of pos for coalesced per-coordinate access ---------------
__global__ void prep_kernel(const float* __restrict__ pos, float* __restrict__ posx,
                            float* __restrict__ posy, float* __restrict__ posz, int N)
{
    const int i = blockIdx.x * blockDim.x + threadIdx.x;
    if (i < N) {
        posx[i] = pos[3 * i + 0];
        posy[i] = pos[3 * i + 1];
        posz[i] = pos[3 * i + 2];
    }
}

// --- Morton-bucket counting sort -> packed pts {x,y,z,bitcast(orig)} --------
__device__ __forceinline__ unsigned spread4(unsigned x)
{
    return (x & 1u) | ((x & 2u) << 2) | ((x & 4u) << 4) | ((x & 8u) << 6);
}
__device__ __forceinline__ unsigned mcode(float x, float y, float z)
{
    int qx = (int)((x + 6.0f) * (16.0f / 12.0f));
    int qy = (int)((y + 6.0f) * (16.0f / 12.0f));
    int qz = (int)((z + 6.0f) * (16.0f / 12.0f));
    qx = qx < 0 ? 0 : (qx > 15 ? 15 : qx);
    qy = qy < 0 ? 0 : (qy > 15 ? 15 : qy);
    qz = qz < 0 ? 0 : (qz > 15 ? 15 : qz);
    return spread4((unsigned)qx) | (spread4((unsigned)qy) << 1)
         | (spread4((unsigned)qz) << 2);
}

__global__ __launch_bounds__(1024) void sort_kernel(
    const float* __restrict__ posx, const float* __restrict__ posy,
    const float* __restrict__ posz, float4* __restrict__ pts, int N)
{
    __shared__ unsigned cnt[4096];
    __shared__ unsigned base[4096];
    const int t = threadIdx.x;

    for (int i = t; i < 4096; i += 1024) cnt[i] = 0;
    __syncthreads();
    for (int i = t; i < N; i += 1024)
        atomicAdd(&cnt[mcode(posx[i], posy[i], posz[i])], 1u);
    __syncthreads();
    if (t == 0) {
        unsigned run = 0;
        for (int c = 0; c < 4096; ++c) { base[c] = run; run += cnt[c]; }
    }
    __syncthreads();
    for (int i = t; i < 4096; i += 1024) cnt[i] = 0;
    __syncthreads();
    for (int i = t; i < N; i += 1024) {
        const float px = posx[i], py = posy[i], pz = posz[i];
        const unsigned m = mcode(px, py, pz);
        const unsigned d = base[m] + atomicAdd(&cnt[m], 1u);
        pts[d] = make_float4(px, py, pz, __uint_as_float((unsigned)i));
    }
}

// --- per-chunk bbox (exact fmin/fmax of member coords) ----------------------
__global__ __launch_bounds__(64) void bbox_kernel(
    const float4* __restrict__ pts, float* __restrict__ bboxG)
{
    const int c = blockIdx.x, l = threadIdx.x;
    const float4 p = pts[c * 64 + l];
    float xmn = p.x, xmx = p.x;
    float ymn = p.y, ymx = p.y;
    float zmn = p.z, zmx = p.z;
#pragma unroll
    for (int off = 32; off > 0; off >>= 1) {
        xmn = fminf(xmn, __shfl_xor(xmn, off));
        xmx = fmaxf(xmx, __shfl_xor(xmx, off));
        ymn = fminf(ymn, __shfl_xor(ymn, off));
        ymx = fmaxf(ymx, __shfl_xor(ymx, off));
        zmn = fminf(zmn, __shfl_xor(zmn, off));
        zmx = fmaxf(zmx, __shfl_xor(zmx, off));
    }
    if (l == 0) {
        float* o = &bboxG[c * 6];
        o[0] = xmn; o[1] = xmx; o[2] = ymn; o[3] = ymx; o[4] = zmn; o[5] = zmx;
    }
}

// --- h = relu(x @ W + b), x[N,64], W[64,128], h[N,128] ----------------------
__global__ __launch_bounds__(256) void mlp_kernel(
    const float* __restrict__ x, const float* __restrict__ W,
    const float* __restrict__ b, float* __restrict__ h, int N)
{
    __shared__ float ws[64 * 128];
    __shared__ float xs[MLP_ROWS * 65];   // +1 pad: breaks 8-way bank conflict
    const int t = threadIdx.x;
    const int r0 = blockIdx.x * MLP_ROWS;

    for (int i = t; i < 64 * 128; i += 256) ws[i] = W[i];
    for (int i = t; i < MLP_ROWS * 64; i += 256) {
        const int r = i >> 6, k = i & 63;
        xs[r * 65 + k] = x[r0 * 64 + i];
    }
    __syncthreads();

    const int tx = t & 31, ty = t >> 5;
    const int c0 = tx * 4, rr = ty * 4;    // 4 rows x 4 cols per thread
    float acc[4][4];
#pragma unroll
    for (int i = 0; i < 4; ++i)
#pragma unroll
        for (int j = 0; j < 4; ++j) acc[i][j] = 0.0f;

    for (int k = 0; k < 64; ++k) {
        const float4 w4 = *(const float4*)(&ws[k * 128 + c0]);
#pragma unroll
        for (int i = 0; i < 4; ++i) {
            const float xv = xs[(rr + i) * 65 + k];
            acc[i][0] += xv * w4.x;
            acc[i][1] += xv * w4.y;
            acc[i][2] += xv * w4.z;
            acc[i][3] += xv * w4.w;
        }
    }
    const float4 b4 = *(const float4*)(&b[c0]);
#pragma unroll
    for (int i = 0; i < 4; ++i) {
        float4 o;
        o.x = fmaxf(acc[i][0] + b4.x, 0.0f);
        o.y = fmaxf(acc[i][1] + b4.y, 0.0f);
        o.z = fmaxf(acc[i][2] + b4.z, 0.0f);
        o.w = fmaxf(acc[i][3] + b4.w, 0.0f);
        *(float4*)(&h[(size_t)(r0 + rr + i) * 128 + c0]) = o;
    }
}

// --- Farthest point sampling: exact, chunk-pruned, 2 barriers/step ----------
__global__ __launch_bounds__(FPS_T) void fps_kernel(
    const float4* __restrict__ pts, const float* __restrict__ bboxG,
    const float* __restrict__ pos, int* __restrict__ out_idx, int M)
{
    __shared__ __align__(16) float mind[32768];   // 128 KB, sorted order
    __shared__ float cmax[NC];                    // max(mind) per chunk
    __shared__ unsigned long long ckey[NC];       // (mbits<<32) | ~orig
    __shared__ float cpx[NC], cpy[NC], cpz[NC];   // chunk winner coords
    __shared__ unsigned alist[NC];
    __shared__ unsigned acnt[2];

    const int t = threadIdx.x;
    const int lane = t & 63;
    const int sg = t & 7;                         // lane within 8-lane group

    for (int i = t; i < 32768; i += FPS_T) mind[i] = __builtin_inff();
    if (t == 0) { acnt[0] = 0; acnt[1] = 0; out_idx[0] = 0; }
    // immutable bbox -> 6 registers (thread t owns chunk t)
    const float bx0 = bboxG[t * 6 + 0], bx1 = bboxG[t * 6 + 1];
    const float by0 = bboxG[t * 6 + 2], by1 = bboxG[t * 6 + 3];
    const float bz0 = bboxG[t * 6 + 4], bz1 = bboxG[t * 6 + 5];

    float lx = pos[0], ly = pos[1], lz = pos[2];  // pick 0 = original index 0
    __syncthreads();

// one-chunk exact update + chunk-key maintenance (r11/r12-validated body)
#define UPD_CHUNK(CC)                                                         \
    {                                                                         \
        float4 p[8];                                                          \
        const int pbase = ((CC) << 6) + (sg << 3);                            \
        _Pragma("unroll")                                                     \
        for (int q = 0; q < 8; ++q) p[q] = pts[pbase + q];                    \
        const int swz = ((CC) & 15) << 2;                                     \
        const int o0 = ((CC) << 6) + ((sg << 3) ^ swz);                       \
        const int o1 = ((CC) << 6) + (((sg << 3) + 4) ^ swz);                 \
        float4 m0 = *(const float4*)&mind[o0];                                \
        float4 m1 = *(const float4*)&mind[o1];                                \
        unsigned long long bkey = 0ULL;                                       \
        float bpx = 0.0f, bpy = 0.0f, bpz = 0.0f;                             \
        PT(0, m0.x) PT(1, m0.y) PT(2, m0.z) PT(3, m0.w)                       \
        PT(4, m1.x) PT(5, m1.y) PT(6, m1.z) PT(7, m1.w)                       \
        *(float4*)&mind[o0] = m0;                                             \
        *(float4*)&mind[o1] = m1;                                             \
        DPPMAX64P(bkey, bpx, bpy, bpz, 0xB1)                                  \
        DPPMAX64P(bkey, bpx, bpy, bpz, 0x4E)                                  \
        DPPMAX64P(bkey, bpx, bpy, bpz, 0x141)                                 \
        if (sg == 0) {                                                        \
            ckey[CC] = bkey;                                                  \
            cmax[CC] = __uint_as_float((unsigned)(bkey >> 32));               \
            cpx[CC] = bpx; cpy[CC] = bpy; cpz[CC] = bpz;                      \
        }                                                                     \
    }
#define PT(q, MC)                                                             \
    {                                                                         \
        const float dx = p[q].x - lx;                                         \
        const float dy = p[q].y - ly;                                         \
        const float dz = p[q].z - lz;                                         \
        const float d = dx * dx + dy * dy + dz * dz;                          \
        MC = fminf(MC, d);                                                    \
        const unsigned long long kq =                                         \
            ((unsigned long long)__float_as_uint(MC) << 32)                   \
            | (unsigned)~__float_as_uint(p[q].w);                             \
        if (kq > bkey) {                                                      \
            bkey = kq; bpx = p[q].x; bpy = p[q].y; bpz = p[q].z;              \
        }                                                                     \
    }

    // ---- prologue: apply pick-0 update to ALL 512 chunks (no alist) --------
    for (int r = (t >> 3); r < NC; r += 64) {
        UPD_CHUNK(r)
    }
    __syncthreads();                                        // barrier B(0)

    for (int s = 1; s < M; ++s) {
        const int buf = s & 1;

        // ---- segment 1: redundant global argmax + bound test + alist -------
        const float cm = cmax[t];                 // post-update, pre-pick state
        unsigned long long gk = ckey[lane];
        unsigned gc = (unsigned)lane;
#pragma unroll
        for (int j = 1; j < 8; ++j) {
            const int c = j * 64 + lane;
            const unsigned long long k = ckey[c];
            if (k > gk) { gk = k; gc = (unsigned)c; }
        }
        DPPMAX64C(gk, gc, 0xB1)
        DPPMAX64C(gk, gc, 0x4E)
        DPPMAX64C(gk, gc, 0x141)
        DPPMAX64C(gk, gc, 0x140)
        DPPMAX64C(gk, gc, 0x142)
        DPPMAX64C(gk, gc, 0x143)
        const unsigned wc = (unsigned)__builtin_amdgcn_readlane((int)gc, 63);
        const unsigned wlo =
            (unsigned)__builtin_amdgcn_readlane((int)(unsigned)gk, 63);
        if (t == 0) out_idx[s] = (int)~wlo;
        lx = cpx[wc]; ly = cpy[wc]; lz = cpz[wc];   // broadcast LDS reads

        const float gx = fmaxf(fmaxf(bx0 - lx, lx - bx1), 0.0f);
        const float gy = fmaxf(fmaxf(by0 - ly, ly - by1), 0.0f);
        const float gz = fmaxf(fmaxf(bz0 - lz, lz - bz1), 0.0f);
        const float dlb = (gx * gx + gy * gy + gz * gz) * 0.99999f;
        if (t == 0) acnt[buf ^ 1] = 0;            // reset opposite parity
        if (dlb < cm)
            alist[atomicAdd(&acnt[buf], 1u)] = (unsigned)t;
        __syncthreads();                                    // barrier A

        // ---- segment 2: exact update of active chunks ----------------------
        const int na = (int)acnt[buf];
        for (int r = (t >> 3); r < na; r += 64) {
            const int cc = (int)alist[r];
            UPD_CHUNK(cc)
        }
        __syncthreads();                                    // barrier B
    }
#undef PT
#undef UPD_CHUNK
}

// --- KNN (exact top-16 by (d, idx)) + gather-max over h + sub outputs -------
__global__ __launch_bounds__(256) void knn_kernel(
    const float* __restrict__ posx, const float* __restrict__ posy,
    const float* __restrict__ posz, const int* __restrict__ idx,
    const float* __restrict__ h, const float* __restrict__ pos,
    const int* __restrict__ batch, float* __restrict__ out,
    float* __restrict__ out_subpos, int* __restrict__ out_subbatch,
    int N, int M, int Cout)
{
    const int q = (int)((blockIdx.x * (unsigned)blockDim.x + threadIdx.x) >> 6);
    const int lane = threadIdx.x & 63;
    if (q >= M) return;

    const int qi = idx[q];
    const float qx = posx[qi], qy = posy[qi], qz = posz[qi];

    // per-lane top-16 (replace-max), wave-shared rejection threshold T
    float d16[KNN_K]; int i16[KNN_K];
#pragma unroll
    for (int k = 0; k < KNN_K; ++k) { d16[k] = __builtin_inff(); i16[k] = 0x7fffffff; }
    float lmax = __builtin_inff();
    int lslot = 0;
    float T = __builtin_inff();

    const int iters = N >> 6;
    for (int c = 0; c < iters; ++c) {
        const int p = c * 64 + lane;
        const float dx = posx[p] - qx;
        const float dy = posy[p] - qy;
        const float dz = posz[p] - qz;
        const float d = dx * dx + dy * dy + dz * dz;
        if (d < T && d < lmax) {
            d16[lslot] = d; i16[lslot] = p;
            lmax = d16[0]; lslot = 0;
#pragma unroll
            for (int k = 1; k < KNN_K; ++k)
                if (d16[k] > lmax) { lmax = d16[k]; lslot = k; }
        }
        if ((c & 31) == 31) {
            float tt = lmax;
#pragma unroll
            for (int off = 32; off > 0; off >>= 1)
                tt = fminf(tt, __shfl_xor(tt, off));
            T = tt;   // global-16th-so-far <= min over lanes of lane-16th: exact reject
        }
    }

    // merge: 16 rounds of wave extract-min with (d, idx) lexicographic order
    int nbr[KNN_K];
#pragma unroll
    for (int r = 0; r < KNN_K; ++r) {
        float lv = d16[0]; int ls = 0;
#pragma unroll
        for (int k = 1; k < KNN_K; ++k)
            if (d16[k] < lv || (d16[k] == lv && i16[k] < i16[ls])) { lv = d16[k]; ls = k; }
        float mv = lv; int mi = i16[ls];
#pragma unroll
        for (int off = 32; off > 0; off >>= 1) {
            const float ov = __shfl_xor(mv, off);
            const int   oi = __shfl_xor(mi, off);
            if (ov < mv || (ov == mv && oi < mi)) { mv = ov; mi = oi; }
        }
        if (i16[ls] == mi) d16[ls] = __builtin_inff();   // unique owner removes it
        nbr[r] = mi;
    }

    // out[q] = max over 16 neighbors of h rows (coalesced per-row loads)
    for (int c = lane; c < Cout; c += 64) {
        float a = -__builtin_inff();
#pragma unroll
        for (int r = 0; r < KNN_K; ++r)
            a = fmaxf(a, h[(size_t)nbr[r] * Cout + c]);
        out[(size_t)q * Cout + c] = a;
    }
    if (lane < 3) out_subpos[q * 3 + lane] = pos[qi * 3 + lane];
    if (lane == 3) out_subbatch[q] = batch[qi];
}

// ---------------------------------------------------------------------------
extern "C" void kernel_launch(void* const* d_in, const int* in_sizes, int n_in,
                              void* d_out, int out_size, void* d_ws, size_t ws_size,
                              hipStream_t stream)
{
    const float* x     = (const float*)d_in[0];
    const float* pos   = (const float*)d_in[1];
    const int*   batch = (const int*)d_in[2];
    const float* W     = (const float*)d_in[3];
    const float* b     = (const float*)d_in[4];

    const int N    = in_sizes[2];       // 32768 (batch has one entry per point)
    const int Cout = in_sizes[4];       // 128
    const int M    = N / 4;             // RATIO = 0.25 -> 8192

    // workspace layout (floats): posx | posy | posz | idx(int) | h[N*Cout]
    float* posx = (float*)d_ws;
    float* posy = posx + N;
    float* posz = posy + N;
    int*   idx  = (int*)(posz + N);
    float* h    = (float*)(idx + M);

    // sort/bbox scratch ALIASES the h region (fps finishes before mlp writes
    // h; single stream serializes): pts (4N floats) | bboxG (3072 floats).
    float4* pts   = (float4*)h;
    float*  bboxG = (float*)(pts + N);

    float* out          = (float*)d_out;
    float* out_subpos   = out + (size_t)M * Cout;
    int*   out_subbatch = (int*)(out_subpos + (size_t)M * 3);

    prep_kernel<<<(N + 255) / 256, 256, 0, stream>>>(pos, posx, posy, posz, N);
    sort_kernel<<<1, 1024, 0, stream>>>(posx, posy, posz, pts, N);
    bbox_kernel<<<NC, 64, 0, stream>>>(pts, bboxG);
    fps_kernel<<<1, FPS_T, 0, stream>>>(pts, bboxG, pos, idx, M);
    mlp_kernel<<<N / MLP_ROWS, 256, 0, stream>>>(x, W, b, h, N);
    knn_kernel<<<(M * 64) / 256, 256, 0, stream>>>(posx, posy, posz, idx, h, pos, batch,
                                                   out, out_subpos, out_subbatch, N, M, Cout);
}

// Round 10
// 13528.700 us; speedup vs baseline: 2.9394x; 1.0486x over previous
//
#include <hip/hip_runtime.h>

// ---------------------------------------------------------------------------
// TransitionDown: FPS (M=N/4) -> KNN(K=16) -> Linear(64->128)+ReLU -> max-pool
// Round 14: consolidation on r11 (the measured-best structure, 1.43us/step;
// r10/r12/r13 restructures all regressed). Three targeted edits only:
//   1. phase 2 carries chunk-winner COORDS through the 3-level DPP payload
//      reduce (r13-validated) -> cpx/cpy/cpz[cc] in LDS (bit-copies of xs/ys/
//      zs floats => pick coords bit-identical to the globals they replace).
//   2. phase 3 carries the chunk ID payload (r13's DPPMAX64C) + wsid slot;
//      pick coords come from one broadcast LDS read cpx[wc] instead of the
//      3 dependent global loads posx/posy/posz[og] (~250-400cyc on the
//      serial chain -> ~120cyc).
//   3. wslot/wsid cross-wave scan packed as b128 reads (14 -> 6 LDS instrs).
// All else byte-identical to r11: dynamic alist distribution, 8-thr/chunk
// update (3x float4 + uint4 loads, mind b128 rmw + XOR bit[2:5] swizzle),
// skip rule dlb*0.99999>=cmax (fmin identity => bit-exact), key
// (mbits<<32)|~orig (max == max-value-then-lowest-orig), 3 barriers/step.
// ---------------------------------------------------------------------------

#define FPS_T   512
#define NC      512
#define KNN_K   16
#define MLP_ROWS 32

#define DPPF(X, CTRL) __uint_as_float(__builtin_amdgcn_update_dpp(            \
    (int)__float_as_uint(X), (int)__float_as_uint(X), (CTRL), 0xf, 0xf, false))
#define DPPU(X, CTRL) ((unsigned)__builtin_amdgcn_update_dpp(                 \
    (int)(X), (int)(X), (CTRL), 0xf, 0xf, false))

// u64 max-combine with 3-float coord payload (r12/r13-validated).
#define DPPMAX64P(KK, PX_, PY_, PZ_, CTRL)                                    \
    {                                                                         \
        const unsigned _lo = (unsigned)(KK), _hi = (unsigned)((KK) >> 32);    \
        const unsigned _nlo = DPPU(_lo, CTRL), _nhi = DPPU(_hi, CTRL);        \
        const float _nx = DPPF(PX_, CTRL);                                    \
        const float _ny = DPPF(PY_, CTRL);                                    \
        const float _nz = DPPF(PZ_, CTRL);                                    \
        const unsigned long long _nk =                                        \
            ((unsigned long long)_nhi << 32) | _nlo;                          \
        if (_nk > (KK)) { KK = _nk; PX_ = _nx; PY_ = _ny; PZ_ = _nz; }        \
    }

// u64 max-combine with u32 chunk-id payload (r13-validated).
#define DPPMAX64C(KK, CC_, CTRL)                                              \
    {                                                                         \
        const unsigned _lo = (unsigned)(KK), _hi = (unsigned)((KK) >> 32);    \
        const unsigned _nlo = DPPU(_lo, CTRL), _nhi = DPPU(_hi, CTRL);        \
        const unsigned _nc = DPPU(CC_, CTRL);                                 \
        const unsigned long long _nk =                                        \
            ((unsigned long long)_nhi << 32) | _nlo;                          \
        if (_nk > (KK)) { KK = _nk; CC_ = _nc; }                              \
    }

// --- SoA transpose of pos for coalesced per-coordinate access ---------------
__global__ void prep_kernel(const float* __restrict__ pos, float* __restrict__ posx,
                            float* __restrict__ posy, float* __restrict__ posz, int N)
{
    const int i = blockIdx.x * blockDim.x + threadIdx.x;
    if (i < N) {
        posx[i] = pos[3 * i + 0];
        posy[i] = pos[3 * i + 1];
        posz[i] = pos[3 * i + 2];
    }
}

// --- Morton-bucket counting sort (spatial permutation; orig idx carried) ----
__device__ __forceinline__ unsigned spread4(unsigned x)
{
    return (x & 1u) | ((x & 2u) << 2) | ((x & 4u) << 4) | ((x & 8u) << 6);
}
__device__ __forceinline__ unsigned mcode(float x, float y, float z)
{
    int qx = (int)((x + 6.0f) * (16.0f / 12.0f));
    int qy = (int)((y + 6.0f) * (16.0f / 12.0f));
    int qz = (int)((z + 6.0f) * (16.0f / 12.0f));
    qx = qx < 0 ? 0 : (qx > 15 ? 15 : qx);
    qy = qy < 0 ? 0 : (qy > 15 ? 15 : qy);
    qz = qz < 0 ? 0 : (qz > 15 ? 15 : qz);
    return spread4((unsigned)qx) | (spread4((unsigned)qy) << 1)
         | (spread4((unsigned)qz) << 2);
}

__global__ __launch_bounds__(1024) void sort_kernel(
    const float* __restrict__ posx, const float* __restrict__ posy,
    const float* __restrict__ posz, float* __restrict__ xs,
    float* __restrict__ ys, float* __restrict__ zs,
    unsigned* __restrict__ orig, int N)
{
    __shared__ unsigned cnt[4096];
    __shared__ unsigned base[4096];
    const int t = threadIdx.x;

    for (int i = t; i < 4096; i += 1024) cnt[i] = 0;
    __syncthreads();
    for (int i = t; i < N; i += 1024)
        atomicAdd(&cnt[mcode(posx[i], posy[i], posz[i])], 1u);
    __syncthreads();
    if (t == 0) {
        unsigned run = 0;
        for (int c = 0; c < 4096; ++c) { base[c] = run; run += cnt[c]; }
    }
    __syncthreads();
    for (int i = t; i < 4096; i += 1024) cnt[i] = 0;
    __syncthreads();
    for (int i = t; i < N; i += 1024) {
        const float px = posx[i], py = posy[i], pz = posz[i];
        const unsigned m = mcode(px, py, pz);
        const unsigned d = base[m] + atomicAdd(&cnt[m], 1u);
        xs[d] = px; ys[d] = py; zs[d] = pz; orig[d] = (unsigned)i;
    }
}

// --- per-chunk bbox (exact fmin/fmax of member coords) ----------------------
__global__ __launch_bounds__(64) void bbox_kernel(
    const float* __restrict__ xs, const float* __restrict__ ys,
    const float* __restrict__ zs, float* __restrict__ bboxG)
{
    const int c = blockIdx.x, l = threadIdx.x;
    const int i = c * 64 + l;
    float xmn = xs[i], xmx = xmn;
    float ymn = ys[i], ymx = ymn;
    float zmn = zs[i], zmx = zmn;
#pragma unroll
    for (int off = 32; off > 0; off >>= 1) {
        xmn = fminf(xmn, __shfl_xor(xmn, off));
        xmx = fmaxf(xmx, __shfl_xor(xmx, off));
        ymn = fminf(ymn, __shfl_xor(ymn, off));
        ymx = fmaxf(ymx, __shfl_xor(ymx, off));
        zmn = fminf(zmn, __shfl_xor(zmn, off));
        zmx = fmaxf(zmx, __shfl_xor(zmx, off));
    }
    if (l == 0) {
        float* o = &bboxG[c * 6];
        o[0] = xmn; o[1] = xmx; o[2] = ymn; o[3] = ymx; o[4] = zmn; o[5] = zmx;
    }
}

// --- h = relu(x @ W + b), x[N,64], W[64,128], h[N,128] ----------------------
__global__ __launch_bounds__(256) void mlp_kernel(
    const float* __restrict__ x, const float* __restrict__ W,
    const float* __restrict__ b, float* __restrict__ h, int N)
{
    __shared__ float ws[64 * 128];
    __shared__ float xs[MLP_ROWS * 65];   // +1 pad: breaks 8-way bank conflict
    const int t = threadIdx.x;
    const int r0 = blockIdx.x * MLP_ROWS;

    for (int i = t; i < 64 * 128; i += 256) ws[i] = W[i];
    for (int i = t; i < MLP_ROWS * 64; i += 256) {
        const int r = i >> 6, k = i & 63;
        xs[r * 65 + k] = x[r0 * 64 + i];
    }
    __syncthreads();

    const int tx = t & 31, ty = t >> 5;
    const int c0 = tx * 4, rr = ty * 4;    // 4 rows x 4 cols per thread
    float acc[4][4];
#pragma unroll
    for (int i = 0; i < 4; ++i)
#pragma unroll
        for (int j = 0; j < 4; ++j) acc[i][j] = 0.0f;

    for (int k = 0; k < 64; ++k) {
        const float4 w4 = *(const float4*)(&ws[k * 128 + c0]);
#pragma unroll
        for (int i = 0; i < 4; ++i) {
            const float xv = xs[(rr + i) * 65 + k];
            acc[i][0] += xv * w4.x;
            acc[i][1] += xv * w4.y;
            acc[i][2] += xv * w4.z;
            acc[i][3] += xv * w4.w;
        }
    }
    const float4 b4 = *(const float4*)(&b[c0]);
#pragma unroll
    for (int i = 0; i < 4; ++i) {
        float4 o;
        o.x = fmaxf(acc[i][0] + b4.x, 0.0f);
        o.y = fmaxf(acc[i][1] + b4.y, 0.0f);
        o.z = fmaxf(acc[i][2] + b4.z, 0.0f);
        o.w = fmaxf(acc[i][3] + b4.w, 0.0f);
        *(float4*)(&h[(size_t)(r0 + rr + i) * 128 + c0]) = o;
    }
}

// --- Farthest point sampling: exact, chunk-pruned (r11 + LDS pick coords) ---
__global__ __launch_bounds__(FPS_T) void fps_kernel(
    const float* __restrict__ xs, const float* __restrict__ ys,
    const float* __restrict__ zs, const unsigned* __restrict__ orig,
    const float* __restrict__ bboxG,
    const float* __restrict__ posx, const float* __restrict__ posy,
    const float* __restrict__ posz, int* __restrict__ out_idx, int M, int N)
{
    __shared__ __align__(16) float mind[32768];   // 128 KB
    __shared__ float cmax[NC];                    // max(mind) per chunk
    __shared__ unsigned long long ckey[NC];       // (mbits<<32) | ~orig
    __shared__ float cpx[NC], cpy[NC], cpz[NC];   // chunk winner coords
    __shared__ unsigned alist[NC];
    __shared__ unsigned acnt[2];
    __shared__ __align__(16) unsigned long long wslot[2][8];
    __shared__ __align__(16) unsigned wsid[2][8];

    const int t = threadIdx.x;
    const int wid = t >> 6;
    const int lane = t & 63;
    const int sg = t & 7;                          // 8-lane subgroup lane

    for (int i = t; i < 32768; i += FPS_T) mind[i] = __builtin_inff();
    cmax[t] = __builtin_inff();
    ckey[t] = 0ULL;
    if (t == 0) { acnt[0] = 0; acnt[1] = 0; out_idx[0] = 0; }
    // immutable bbox -> 6 registers per thread (chunk t)
    const float bxmn = bboxG[t * 6 + 0], bxmx = bboxG[t * 6 + 1];
    const float bymn = bboxG[t * 6 + 2], bymx = bboxG[t * 6 + 3];
    const float bzmn = bboxG[t * 6 + 4], bzmx = bboxG[t * 6 + 5];
    __syncthreads();

    float lx = posx[0], ly = posy[0], lz = posz[0];   // pick 0 = index 0

    for (int s = 1; s < M; ++s) {
        const int buf = s & 1;

        // ---- phase 1: bound test, chunk t (bbox in regs) -------------------
        {
            const float gx = fmaxf(fmaxf(bxmn - lx, lx - bxmx), 0.0f);
            const float gy = fmaxf(fmaxf(bymn - ly, ly - bymx), 0.0f);
            const float gz = fmaxf(fmaxf(bzmn - lz, lz - bzmx), 0.0f);
            const float dlb = (gx * gx + gy * gy + gz * gz) * 0.99999f;
            if (dlb < cmax[t])
                alist[atomicAdd(&acnt[buf], 1u)] = (unsigned)t;
        }
        __syncthreads();                                   // A
        const int na = (int)acnt[buf];

        // ---- phase 2: 8 threads per active chunk, key + coord payload ------
        for (int r = (t >> 3); r < na; r += 64) {
            const int cc = (int)alist[r];
            unsigned long long key = 0ULL;
            float bpx = 0.0f, bpy = 0.0f, bpz = 0.0f;
#pragma unroll
            for (int hh = 0; hh < 2; ++hh) {
                const int p = (cc << 6) + sg * 8 + hh * 4;      // sorted idx
                const float4 x4 = *(const float4*)&xs[p];
                const float4 y4 = *(const float4*)&ys[p];
                const float4 z4 = *(const float4*)&zs[p];
                const uint4  o4 = *(const uint4*)&orig[p];
                const int lb = (cc << 6) + ((sg * 8 + hh * 4) ^ ((cc & 15) << 2));
                float4 m4 = *(const float4*)&mind[lb];
                float dx, dy, dz, d;
                dx = x4.x - lx; dy = y4.x - ly; dz = z4.x - lz;
                d = dx * dx + dy * dy + dz * dz;
                m4.x = fminf(m4.x, d);
                { const unsigned long long k =
                      ((unsigned long long)__float_as_uint(m4.x) << 32)
                      | (unsigned)~o4.x;
                  if (k > key) { key = k; bpx = x4.x; bpy = y4.x; bpz = z4.x; } }
                dx = x4.y - lx; dy = y4.y - ly; dz = z4.y - lz;
                d = dx * dx + dy * dy + dz * dz;
                m4.y = fminf(m4.y, d);
                { const unsigned long long k =
                      ((unsigned long long)__float_as_uint(m4.y) << 32)
                      | (unsigned)~o4.y;
                  if (k > key) { key = k; bpx = x4.y; bpy = y4.y; bpz = z4.y; } }
                dx = x4.z - lx; dy = y4.z - ly; dz = z4.z - lz;
                d = dx * dx + dy * dy + dz * dz;
                m4.z = fminf(m4.z, d);
                { const unsigned long long k =
                      ((unsigned long long)__float_as_uint(m4.z) << 32)
                      | (unsigned)~o4.z;
                  if (k > key) { key = k; bpx = x4.z; bpy = y4.z; bpz = z4.z; } }
                dx = x4.w - lx; dy = y4.w - ly; dz = z4.w - lz;
                d = dx * dx + dy * dy + dz * dz;
                m4.w = fminf(m4.w, d);
                { const unsigned long long k =
                      ((unsigned long long)__float_as_uint(m4.w) << 32)
                      | (unsigned)~o4.w;
                  if (k > key) { key = k; bpx = x4.w; bpy = y4.w; bpz = z4.w; } }
                *(float4*)&mind[lb] = m4;
            }
            // reduce over the 8-lane subgroup: xor1, xor2, half-mirror
            DPPMAX64P(key, bpx, bpy, bpz, 0xB1)
            DPPMAX64P(key, bpx, bpy, bpz, 0x4E)
            DPPMAX64P(key, bpx, bpy, bpz, 0x141)
            if (sg == 0) {
                ckey[cc] = key;
                cmax[cc] = __uint_as_float((unsigned)(key >> 32));
                cpx[cc] = bpx; cpy[cc] = bpy; cpz[cc] = bpz;
            }
        }
        __syncthreads();                                   // B

        // ---- phase 3: global argmax over 512 chunk keys + id payload -------
        {
            unsigned long long k3 = ckey[t];
            unsigned gc = (unsigned)t;
            DPPMAX64C(k3, gc, 0xB1)
            DPPMAX64C(k3, gc, 0x4E)
            DPPMAX64C(k3, gc, 0x141)
            DPPMAX64C(k3, gc, 0x140)
            DPPMAX64C(k3, gc, 0x142)
            DPPMAX64C(k3, gc, 0x143)
            if (lane == 63) { wslot[buf][wid] = k3; wsid[buf][wid] = gc; }
        }
        if (t == 0) acnt[buf] = 0;                         // reuse at s+2
        __syncthreads();                                   // C

        // packed scan of 8 wave winners: 4x b128 keys + 2x b128 ids
        const ulonglong2* kp = (const ulonglong2*)&wslot[buf][0];
        const ulonglong2 ka = kp[0], kb = kp[1], kc = kp[2], kd = kp[3];
        const uint4 ia = *(const uint4*)&wsid[buf][0];
        const uint4 ib = *(const uint4*)&wsid[buf][4];
        unsigned long long wk = ka.x; unsigned wc = ia.x;
        if (ka.y > wk) { wk = ka.y; wc = ia.y; }
        if (kb.x > wk) { wk = kb.x; wc = ia.z; }
        if (kb.y > wk) { wk = kb.y; wc = ia.w; }
        if (kc.x > wk) { wk = kc.x; wc = ib.x; }
        if (kc.y > wk) { wk = kc.y; wc = ib.y; }
        if (kd.x > wk) { wk = kd.x; wc = ib.z; }
        if (kd.y > wk) { wk = kd.y; wc = ib.w; }

        const unsigned og = ~(unsigned)wk;                 // original index
        if (t == 0) out_idx[s] = (int)og;
        lx = cpx[wc]; ly = cpy[wc]; lz = cpz[wc];          // broadcast LDS
        // wslot/wsid/acnt[buf] next rewritten at s+2, >=2 barriers later.
    }
}

// --- KNN (exact top-16 by (d, idx)) + gather-max over h + sub outputs -------
__global__ __launch_bounds__(256) void knn_kernel(
    const float* __restrict__ posx, const float* __restrict__ posy,
    const float* __restrict__ posz, const int* __restrict__ idx,
    const float* __restrict__ h, const float* __restrict__ pos,
    const int* __restrict__ batch, float* __restrict__ out,
    float* __restrict__ out_subpos, int* __restrict__ out_subbatch,
    int N, int M, int Cout)
{
    const int q = (int)((blockIdx.x * (unsigned)blockDim.x + threadIdx.x) >> 6);
    const int lane = threadIdx.x & 63;
    if (q >= M) return;

    const int qi = idx[q];
    const float qx = posx[qi], qy = posy[qi], qz = posz[qi];

    // per-lane top-16 (replace-max), wave-shared rejection threshold T
    float d16[KNN_K]; int i16[KNN_K];
#pragma unroll
    for (int k = 0; k < KNN_K; ++k) { d16[k] = __builtin_inff(); i16[k] = 0x7fffffff; }
    float lmax = __builtin_inff();
    int lslot = 0;
    float T = __builtin_inff();

    const int iters = N >> 6;
    for (int c = 0; c < iters; ++c) {
        const int p = c * 64 + lane;
        const float dx = posx[p] - qx;
        const float dy = posy[p] - qy;
        const float dz = posz[p] - qz;
        const float d = dx * dx + dy * dy + dz * dz;
        if (d < T && d < lmax) {
            d16[lslot] = d; i16[lslot] = p;
            lmax = d16[0]; lslot = 0;
#pragma unroll
            for (int k = 1; k < KNN_K; ++k)
                if (d16[k] > lmax) { lmax = d16[k]; lslot = k; }
        }
        if ((c & 31) == 31) {
            float tt = lmax;
#pragma unroll
            for (int off = 32; off > 0; off >>= 1)
                tt = fminf(tt, __shfl_xor(tt, off));
            T = tt;   // global-16th-so-far <= min over lanes of lane-16th: exact reject
        }
    }

    // merge: 16 rounds of wave extract-min with (d, idx) lexicographic order
    int nbr[KNN_K];
#pragma unroll
    for (int r = 0; r < KNN_K; ++r) {
        float lv = d16[0]; int ls = 0;
#pragma unroll
        for (int k = 1; k < KNN_K; ++k)
            if (d16[k] < lv || (d16[k] == lv && i16[k] < i16[ls])) { lv = d16[k]; ls = k; }
        float mv = lv; int mi = i16[ls];
#pragma unroll
        for (int off = 32; off > 0; off >>= 1) {
            const float ov = __shfl_xor(mv, off);
            const int   oi = __shfl_xor(mi, off);
            if (ov < mv || (ov == mv && oi < mi)) { mv = ov; mi = oi; }
        }
        if (i16[ls] == mi) d16[ls] = __builtin_inff();   // unique owner removes it
        nbr[r] = mi;
    }

    // out[q] = max over 16 neighbors of h rows (coalesced per-row loads)
    for (int c = lane; c < Cout; c += 64) {
        float a = -__builtin_inff();
#pragma unroll
        for (int r = 0; r < KNN_K; ++r)
            a = fmaxf(a, h[(size_t)nbr[r] * Cout + c]);
        out[(size_t)q * Cout + c] = a;
    }
    if (lane < 3) out_subpos[q * 3 + lane] = pos[qi * 3 + lane];
    if (lane == 3) out_subbatch[q] = batch[qi];
}

// ---------------------------------------------------------------------------
extern "C" void kernel_launch(void* const* d_in, const int* in_sizes, int n_in,
                              void* d_out, int out_size, void* d_ws, size_t ws_size,
                              hipStream_t stream)
{
    const float* x     = (const float*)d_in[0];
    const float* pos   = (const float*)d_in[1];
    const int*   batch = (const int*)d_in[2];
    const float* W     = (const float*)d_in[3];
    const float* b     = (const float*)d_in[4];

    const int N    = in_sizes[2];       // 32768 (batch has one entry per point)
    const int Cout = in_sizes[4];       // 128
    const int M    = N / 4;             // RATIO = 0.25 -> 8192

    // workspace layout (floats): posx | posy | posz | idx(int) | h[N*Cout]
    float* posx = (float*)d_ws;
    float* posy = posx + N;
    float* posz = posy + N;
    int*   idx  = (int*)(posz + N);
    float* h    = (float*)(idx + M);

    // sort/bbox scratch ALIASES the h region (fps finishes before mlp writes
    // h; single stream serializes): xs|ys|zs|orig|bboxG = 4N + 3072 floats.
    float*    xs    = h;
    float*    ys    = xs + N;
    float*    zs    = ys + N;
    unsigned* orig  = (unsigned*)(zs + N);
    float*    bboxG = (float*)(orig + N);

    float* out          = (float*)d_out;
    float* out_subpos   = out + (size_t)M * Cout;
    int*   out_subbatch = (int*)(out_subpos + (size_t)M * 3);

    prep_kernel<<<(N + 255) / 256, 256, 0, stream>>>(pos, posx, posy, posz, N);
    sort_kernel<<<1, 1024, 0, stream>>>(posx, posy, posz, xs, ys, zs, orig, N);
    bbox_kernel<<<NC, 64, 0, stream>>>(xs, ys, zs, bboxG);
    fps_kernel<<<1, FPS_T, 0, stream>>>(xs, ys, zs, orig, bboxG,
                                        posx, posy, posz, idx, M, N);
    mlp_kernel<<<N / MLP_ROWS, 256, 0, stream>>>(x, W, b, h, N);
    knn_kernel<<<(M * 64) / 256, 256, 0, stream>>>(posx, posy, posz, idx, h, pos, batch,
                                                   out, out_subpos, out_subbatch, N, M, Cout);
}